// Round 1
// baseline (423.532 us; speedup 1.0000x reference)
//
#include <hip/hip_runtime.h>
#include <hip/hip_fp16.h>
#include <math.h>

#define NN 100000
#define EE 1600000
#define EP (EE + NN)   // edges incl. self-loops
#define NEG 0.2f
#define TN 128         // fused tile: nodes per block
#define NB 391         // ceil(NN/256)
#define CHUNK 4096     // partition chunk (8 edges/thread * 512)
#define SSTRIDE 5120   // arena slots per bucket
#define SCAP 5120      // LDS staging capacity in csr_scatter_k

typedef __attribute__((ext_vector_type(2))) float floatx2;

__device__ inline unsigned pk_fp8x4(float a, float b, float c, float d) {
    unsigned r = __builtin_amdgcn_cvt_pk_fp8_f32(a, b, 0u, false);
    r = __builtin_amdgcn_cvt_pk_fp8_f32(c, d, r, true);
    return r;
}

// Packed accumulate: 4x v_pk_fma_f32 instead of 8x v_fma_f32.
__device__ __forceinline__ void accum_fp8p(uint2 raw, float p, floatx2* acc) {
    floatx2 p2; p2[0] = p; p2[1] = p;
    acc[0] += p2 * __builtin_amdgcn_cvt_pk_f32_fp8(raw.x, false);
    acc[1] += p2 * __builtin_amdgcn_cvt_pk_f32_fp8(raw.x, true);
    acc[2] += p2 * __builtin_amdgcn_cvt_pk_f32_fp8(raw.y, false);
    acc[3] += p2 * __builtin_amdgcn_cvt_pk_f32_fp8(raw.y, true);
}

// Wave-level inclusive scan over 64 lanes.
__device__ __forceinline__ int wave_iscan(int v, int lane) {
#pragma unroll
    for (int o = 1; o < 64; o <<= 1) {
        int t = __shfl_up(v, o);
        if (lane >= o) v += t;
    }
    return v;
}

// Swizzled byte offset into the fp16 node tile hbuf[TN][64].
// Row = 128 B = 8 x 16B slots; slot XOR (n>>2)&7 spreads the GEMM's
// fixed-slot column reads (4 consecutive r-groups) across 4 distinct bank
// groups -> conflict-free b128 reads; per-row writes stay a permutation of
// the contiguous 128 B (2-way on half writes = free).
__device__ __forceinline__ int hoff(int nl, int slot) {
    return (nl << 7) + (((slot ^ (nl >> 2)) & 7) << 4);
}

// 128x64 @ 64x64 GEMM straight from swizzled fp16 LDS; W column block held
// in 8 float4 registers per thread. c = out-col group (4 cols), r = node
// group (4 nodes). No fp32 transpose staging needed.
__device__ __forceinline__ void gemm64_lds(const unsigned short* hbuf, const float* Wl,
                                           int c, int r, float acc[4][4]) {
#pragma unroll
    for (int i = 0; i < 4; i++)
#pragma unroll
        for (int j = 0; j < 4; j++) acc[i][j] = 0.f;
    for (int kb = 0; kb < 8; kb++) {
        float4 w[8];
#pragma unroll
        for (int kk = 0; kk < 8; kk++) w[kk] = *(const float4*)&Wl[(kb * 8 + kk) * 64 + c * 4];
#pragma unroll
        for (int i = 0; i < 4; i++) {
            int nl = r * 4 + i;
            uint4 a = *(const uint4*)((const char*)hbuf + hoff(nl, kb));
            const __half2* hh = (const __half2*)&a;
#pragma unroll
            for (int kk = 0; kk < 4; kk++) {
                float2 f = __half22float2(hh[kk]);
                acc[i][0] += f.x * w[2 * kk].x + f.y * w[2 * kk + 1].x;
                acc[i][1] += f.x * w[2 * kk].y + f.y * w[2 * kk + 1].y;
                acc[i][2] += f.x * w[2 * kk].z + f.y * w[2 * kk + 1].z;
                acc[i][3] += f.x * w[2 * kk].w + f.y * w[2 * kk + 1].w;
            }
        }
    }
}

// Transform epilogue: fp8-pack h, compute es/ed via 4-lane shfl reduce.
__device__ __forceinline__ void trans_epi(const float acc[4][4], const float* as_, const float* ad_,
                                          unsigned char* h8o, float* eso, float* edo,
                                          int n0, int c, int r) {
    int head = c >> 2, qq = c & 3;
    float as0v = as_[head * 16 + qq * 4], as1v = as_[head * 16 + qq * 4 + 1];
    float as2v = as_[head * 16 + qq * 4 + 2], as3v = as_[head * 16 + qq * 4 + 3];
    float ad0v = ad_[head * 16 + qq * 4], ad1v = ad_[head * 16 + qq * 4 + 1];
    float ad2v = ad_[head * 16 + qq * 4 + 2], ad3v = ad_[head * 16 + qq * 4 + 3];
#pragma unroll
    for (int i = 0; i < 4; i++) {
        int n = n0 + r * 4 + i;
        float pes = acc[i][0] * as0v + acc[i][1] * as1v + acc[i][2] * as2v + acc[i][3] * as3v;
        float ped = acc[i][0] * ad0v + acc[i][1] * ad1v + acc[i][2] * ad2v + acc[i][3] * ad3v;
        pes += __shfl_xor(pes, 1); pes += __shfl_xor(pes, 2);
        ped += __shfl_xor(ped, 1); ped += __shfl_xor(ped, 2);
        if (n < NN) {
            unsigned rq = pk_fp8x4(acc[i][0], acc[i][1], acc[i][2], acc[i][3]);
            *(unsigned*)(h8o + ((size_t)n << 6) + (c << 2)) = rq;
            if (qq == 0) { eso[n * 4 + head] = pes; edo[n * 4 + head] = ped; }
        }
    }
}

// Fused edge softmax + gather for a 128-node tile: 8 waves x 8 pair-rounds,
// 2 nodes/wave/round (same inner loop as the proven standalone gather_k),
// output written to the swizzled LDS tile instead of global fp16.
__device__ __forceinline__ void gather_rounds(const unsigned char* __restrict__ h8i,
                                              const float* __restrict__ esi, const float* __restrict__ edi,
                                              const int* __restrict__ rowptr, const int* __restrict__ edge_src,
                                              const float* __restrict__ bg,
                                              unsigned short* hbuf, int n0, int tid) {
    int lane = tid & 63, wid = tid >> 6;
    int q = lane >> 3, j = lane & 7, head = j >> 1;
    const unsigned char* h8j = h8i + (j << 3);
    const float4* bp = (const float4*)(bg + j * 8);
    float4 bb0 = bp[0], bb1 = bp[1];
    for (int rr = 0; rr < 8; rr++) {
        int nlA = wid * 16 + rr * 2;
        int nA = n0 + nlA;
        if (nA >= NN) break;   // wave-uniform; nA monotone in rr
        int nB = nA + 1;
        bool hasB = nB < NN;
        int begA = rowptr[nA], endA = rowptr[nA + 1];
        int begB = hasB ? rowptr[nB] : begA, endB = hasB ? rowptr[nB + 1] : begA;
        float edvA = edi[nA * 4 + head];
        float edvB = hasB ? edi[nB * 4 + head] : 0.f;
        floatx2 accA[4], accB[4];
#pragma unroll
        for (int t = 0; t < 4; t++) { accA[t] = (floatx2)(0.f); accB[t] = (floatx2)(0.f); }
        float sA = 0.f, sB = 0.f;
        int iters = max((endA - begA + 7) >> 3, (endB - begB + 7) >> 3);
        for (int k = 0; k < iters; k++) {
            int eA = begA + (k << 3) + q;
            int eB = begB + (k << 3) + q;
            bool vA = eA < endA;
            bool vB = eB < endB;
            int srcA = edge_src[vA ? eA : begA];
            int srcB = edge_src[vB ? eB : begB];
            uint2 rawA = *(const uint2*)(h8j + ((unsigned)srcA << 6));
            float esvA = esi[srcA * 4 + head];
            uint2 rawB = *(const uint2*)(h8j + ((unsigned)srcB << 6));
            float esvB = esi[srcB * 4 + head];
            float evA = esvA + edvA; evA = evA > 0.f ? evA : NEG * evA;
            float evB = esvB + edvB; evB = evB > 0.f ? evB : NEG * evB;
            float pA = vA ? __expf(evA) : 0.f;
            float pB = vB ? __expf(evB) : 0.f;
            accum_fp8p(rawA, pA, accA);
            accum_fp8p(rawB, pB, accB);
            sA += pA;
            sB += pB;
        }
        float fA[8], fB[8];
#pragma unroll
        for (int t = 0; t < 4; t++) {
            fA[2 * t] = accA[t][0]; fA[2 * t + 1] = accA[t][1];
            fB[2 * t] = accB[t][0]; fB[2 * t + 1] = accB[t][1];
        }
#pragma unroll
        for (int t = 0; t < 8; t++) {
            fA[t] += __shfl_xor(fA[t], 8);
            fA[t] += __shfl_xor(fA[t], 16);
            fA[t] += __shfl_xor(fA[t], 32);
            fB[t] += __shfl_xor(fB[t], 8);
            fB[t] += __shfl_xor(fB[t], 16);
            fB[t] += __shfl_xor(fB[t], 32);
        }
        sA += __shfl_xor(sA, 8); sA += __shfl_xor(sA, 16); sA += __shfl_xor(sA, 32);
        sB += __shfl_xor(sB, 8); sB += __shfl_xor(sB, 16); sB += __shfl_xor(sB, 32);
        if (q == 0) {
            {
                float inv = 1.0f / (sA + 1e-16f);
                union { __half2 h2[4]; uint4 u; } pk;
                pk.h2[0] = __floats2half2_rn(fA[0] * inv + bb0.x, fA[1] * inv + bb0.y);
                pk.h2[1] = __floats2half2_rn(fA[2] * inv + bb0.z, fA[3] * inv + bb0.w);
                pk.h2[2] = __floats2half2_rn(fA[4] * inv + bb1.x, fA[5] * inv + bb1.y);
                pk.h2[3] = __floats2half2_rn(fA[6] * inv + bb1.z, fA[7] * inv + bb1.w);
                *(uint4*)((char*)hbuf + hoff(nlA, j)) = pk.u;
            }
            if (hasB) {
                float inv = 1.0f / (sB + 1e-16f);
                union { __half2 h2[4]; uint4 u; } pk;
                pk.h2[0] = __floats2half2_rn(fB[0] * inv + bb0.x, fB[1] * inv + bb0.y);
                pk.h2[1] = __floats2half2_rn(fB[2] * inv + bb0.z, fB[3] * inv + bb0.w);
                pk.h2[2] = __floats2half2_rn(fB[4] * inv + bb1.x, fB[5] * inv + bb1.y);
                pk.h2[3] = __floats2half2_rn(fB[6] * inv + bb1.z, fB[7] * inv + bb1.w);
                *(uint4*)((char*)hbuf + hoff(nlA + 1, j)) = pk.u;
            }
        }
    }
}

// ---------------- Bucketed CSR build (unchanged, proven) ----------------

__global__ __launch_bounds__(512) void partition_k(const int* __restrict__ ei, int* __restrict__ gcur,
                                                   unsigned int* __restrict__ arena) {
    __shared__ int lh[512], lcur[512], lbase[512];
    __shared__ int wsum[8];
    __shared__ unsigned int staged[CHUNK];
    __shared__ unsigned short stb[CHUNK];
    int tid = threadIdx.x;
    int lane = tid & 63, wid = tid >> 6;
    int c0 = blockIdx.x * CHUNK;
    int csize = min(CHUNK, EP - c0);
    lh[tid] = 0;
    __syncthreads();
    unsigned int myv[8];
    int myb[8];
#pragma unroll
    for (int i = 0; i < 8; i++) {
        int e = c0 + i * 512 + tid;
        if (e < c0 + csize) {
            int d = (e < EE) ? ei[EE + e] : (e - EE);
            int sv = (e < EE) ? ei[e] : d;
            int b = d >> 8;
            myv[i] = ((unsigned)(d - (b << 8)) << 17) | (unsigned)sv;
            myb[i] = b;
            atomicAdd(&lh[b], 1);
        } else myb[i] = -1;
    }
    __syncthreads();
    int v = lh[tid];
    int isc = wave_iscan(v, lane);
    if (lane == 63) wsum[wid] = isc;
    __syncthreads();
    if (tid == 0) {
        int run = 0;
#pragma unroll
        for (int w = 0; w < 8; w++) { int t = wsum[w]; wsum[w] = run; run += t; }
    }
    __syncthreads();
    int excl = isc - v + wsum[wid];
    lcur[tid] = excl;
    __syncthreads();
#pragma unroll
    for (int i = 0; i < 8; i++) {
        if (myb[i] >= 0) {
            int idx = atomicAdd(&lcur[myb[i]], 1);
            staged[idx] = myv[i];
            stb[idx] = (unsigned short)myb[i];
        }
    }
    __syncthreads();
    if (tid < NB && v > 0) {
        int base = atomicAdd(&gcur[tid], v);
        lbase[tid] = tid * SSTRIDE + base - excl;
    }
    __syncthreads();
    for (int i = tid; i < csize; i += 512) {
        unsigned int val = staged[i];
        arena[lbase[stb[i]] + i] = val;
    }
}

__global__ __launch_bounds__(512) void bscan_k(const int* __restrict__ gcur, int* __restrict__ bbase,
                                               int* __restrict__ rowptr) {
    __shared__ int s[512];
    int tid = threadIdx.x;
    int v = (tid < NB) ? gcur[tid] : 0;
    s[tid] = v;
    __syncthreads();
    for (int o = 1; o < 512; o <<= 1) {
        int t = (tid >= o) ? s[tid - o] : 0;
        __syncthreads();
        s[tid] += t;
        __syncthreads();
    }
    int excl = s[tid] - v;
    if (tid <= NB) bbase[tid] = excl;
    if (tid == 0) rowptr[NN] = EP;
}

__global__ __launch_bounds__(512) void csr_scatter_k(const int* __restrict__ bbase, const int* __restrict__ gcur,
                                                     const unsigned int* __restrict__ arena,
                                                     int* __restrict__ rowptr, int* __restrict__ edge_src) {
    __shared__ int cnt[256], sc[256];
    __shared__ int wsum[4];
    __shared__ unsigned int stg[SCAP];
    int tid = threadIdx.x;
    int b = blockIdx.x;
    int e0 = bbase[b];
    int sz = gcur[b];
    int abase = b * SSTRIDE;
    if (tid < 256) cnt[tid] = 0;
    __syncthreads();
    for (int i = tid; i < sz; i += 512) {
        unsigned int v = arena[abase + i];
        if (i < SCAP) stg[i] = v;
        atomicAdd(&cnt[v >> 17], 1);
    }
    __syncthreads();
    if (tid < 256) {
        int lane = tid & 63, wid = tid >> 6;
        int v = cnt[tid];
        int isc = wave_iscan(v, lane);
        if (lane == 63) wsum[wid] = isc;
        __syncthreads();
        if (tid == 0) {
            int run = 0;
#pragma unroll
            for (int w = 0; w < 4; w++) { int t = wsum[w]; wsum[w] = run; run += t; }
        }
        __syncthreads();
        int excl = isc - v + wsum[wid];
        int d = (b << 8) + tid;
        if (d < NN) rowptr[d] = e0 + excl;
        sc[tid] = excl;
    } else {
        __syncthreads();
        __syncthreads();
    }
    __syncthreads();
    for (int i = tid; i < sz; i += 512) {
        unsigned int val = (i < SCAP) ? stg[i] : arena[abase + i];
        int dl = val >> 17;
        int p = atomicAdd(&sc[dl], 1);
        edge_src[e0 + p] = (int)(val & 0x1FFFFu);
    }
}

// ---------------- Fused layer 0 gather (rank-1) + W1 transform ----------------

__global__ __launch_bounds__(512) void g0t_k(const float* __restrict__ x, const float* __restrict__ W0,
                                             const float* __restrict__ as0_, const float* __restrict__ ad0_,
                                             const float* __restrict__ b0_,
                                             const int* __restrict__ rowptr, const int* __restrict__ edge_src,
                                             const float* __restrict__ W1, const float* __restrict__ as1_,
                                             const float* __restrict__ ad1_,
                                             unsigned char* __restrict__ h8o, float* __restrict__ eso,
                                             float* __restrict__ edo) {
    __shared__ __align__(16) unsigned short hbuf[TN * 64];
    __shared__ float Wl[4096];
    __shared__ float W0l[64], asl[64], adl[64], bl[64];
    int tid = threadIdx.x;
    for (int i = tid; i < 4096; i += 512) Wl[i] = W1[i];
    if (tid < 64) { W0l[tid] = W0[tid]; asl[tid] = as0_[tid]; adl[tid] = ad0_[tid]; bl[tid] = b0_[tid]; }
    __syncthreads();
    int n0 = blockIdx.x * TN;
    int lane = tid & 63, wid = tid >> 6;
    int q4 = lane >> 2, head4 = lane & 3;
    float cs = 0.f, cd = 0.f;
#pragma unroll
    for (int cc = 0; cc < 16; cc++) {
        float w = W0l[head4 * 16 + cc];
        cs += w * asl[head4 * 16 + cc];
        cd += w * adl[head4 * 16 + cc];
    }
    for (int rr = 0; rr < 16; rr++) {
        int nl = wid * 16 + rr;
        int wv = n0 + nl;
        if (wv >= NN) break;   // wave-uniform
        int beg = rowptr[wv], end = rowptr[wv + 1];
        float xd = x[wv];
        float num = 0.f, den = 0.f;
        for (int e0 = beg; e0 < end; e0 += 16) {
            int e = e0 + q4;
            bool vld = e < end;
            int ee = vld ? e : (end - 1);
            int src = edge_src[ee];
            float xs = x[src];
            float ev = xs * cs + xd * cd;
            ev = ev > 0.f ? ev : NEG * ev;
            float p = vld ? __expf(ev) : 0.f;
            num += p * xs;
            den += p;
        }
        num += __shfl_xor(num, 4);  num += __shfl_xor(num, 8);
        num += __shfl_xor(num, 16); num += __shfl_xor(num, 32);
        den += __shfl_xor(den, 4);  den += __shfl_xor(den, 8);
        den += __shfl_xor(den, 16); den += __shfl_xor(den, 32);
        float nh = __shfl(num, lane >> 4);
        float dh = __shfl(den, lane >> 4);
        float val = nh / (dh + 1e-16f);
        float hv = val * W0l[lane] + bl[lane];
        *(__half*)((char*)hbuf + hoff(nl, lane >> 3) + ((lane & 7) << 1)) = __float2half(hv);
    }
    __syncthreads();
    int c = tid & 15, r = tid >> 4;
    float acc[4][4];
    gemm64_lds(hbuf, Wl, c, r, acc);
    trans_epi(acc, as1_, ad1_, h8o, eso, edo, n0, c, r);
}

// ---------------- Fused gather + next-layer transform ----------------

__global__ __launch_bounds__(512) void gt_k(const unsigned char* __restrict__ h8i, const float* __restrict__ esi,
                                            const float* __restrict__ edi, const int* __restrict__ rowptr,
                                            const int* __restrict__ edge_src, const float* __restrict__ bg,
                                            const float* __restrict__ W, const float* __restrict__ as_,
                                            const float* __restrict__ ad_,
                                            unsigned char* __restrict__ h8o, float* __restrict__ eso,
                                            float* __restrict__ edo) {
    __shared__ __align__(16) unsigned short hbuf[TN * 64];
    __shared__ float Wl[4096];
    int tid = threadIdx.x;
    for (int i = tid; i < 4096; i += 512) Wl[i] = W[i];
    int n0 = blockIdx.x * TN;
    gather_rounds(h8i, esi, edi, rowptr, edge_src, bg, hbuf, n0, tid);
    __syncthreads();
    int c = tid & 15, r = tid >> 4;
    float acc[4][4];
    gemm64_lds(hbuf, Wl, c, r, acc);
    trans_epi(acc, as_, ad_, h8o, eso, edo, n0, c, r);
}

// ---------------- Fused gather + MLP + decoder + softmax ----------------

__global__ __launch_bounds__(512) void gm_k(const unsigned char* __restrict__ h8i, const float* __restrict__ esi,
                                            const float* __restrict__ edi, const int* __restrict__ rowptr,
                                            const int* __restrict__ edge_src, const float* __restrict__ bg,
                                            const float* __restrict__ lw1, const float* __restrict__ lb1,
                                            const float* __restrict__ lw2, const float* __restrict__ lb2,
                                            const float* __restrict__ dw, const float* __restrict__ db,
                                            float* __restrict__ out) {
    __shared__ __align__(16) unsigned short hbuf[TN * 64];
    __shared__ float W1l[4096];
    __shared__ float W2l[1024];
    __shared__ float a2t[16 * 132];   // padded stride 132: breaks 16-way write conflict
    __shared__ float lb1l[64], lb2l[16], dwl[64], dbl[4];
    int tid = threadIdx.x;
    for (int i = tid; i < 4096; i += 512) W1l[i] = lw1[i];
    for (int i = tid; i < 1024; i += 512) W2l[i] = lw2[i];
    if (tid < 64) { lb1l[tid] = lb1[tid]; dwl[tid] = dw[tid]; }
    if (tid < 16) lb2l[tid] = lb2[tid];
    if (tid < 4) dbl[tid] = db[tid];
    int n0 = blockIdx.x * TN;
    gather_rounds(h8i, esi, edi, rowptr, edge_src, bg, hbuf, n0, tid);
    __syncthreads();
    int c = tid & 15, r = tid >> 4;
    float acc[4][4];
    gemm64_lds(hbuf, W1l, c, r, acc);   // h @ lw1
#pragma unroll
    for (int i = 0; i < 4; i++) {
        acc[i][0] = fmaxf(acc[i][0] + lb1l[c * 4 + 0], 0.f);
        acc[i][1] = fmaxf(acc[i][1] + lb1l[c * 4 + 1], 0.f);
        acc[i][2] = fmaxf(acc[i][2] + lb1l[c * 4 + 2], 0.f);
        acc[i][3] = fmaxf(acc[i][3] + lb1l[c * 4 + 3], 0.f);
    }
    __syncthreads();   // all GEMM1 reads of hbuf complete before overwrite
#pragma unroll
    for (int i = 0; i < 4; i++) {   // a1 (fp16) back into hbuf, same swizzle
        int nl = r * 4 + i;
        union { __half2 h2[2]; uint2 u; } pk;
        pk.h2[0] = __floats2half2_rn(acc[i][0], acc[i][1]);
        pk.h2[1] = __floats2half2_rn(acc[i][2], acc[i][3]);
        *(uint2*)((char*)hbuf + hoff(nl, c >> 1) + ((c & 1) << 3)) = pk.u;
    }
    __syncthreads();
    float acc2[4] = {0.f, 0.f, 0.f, 0.f};   // a1 @ lw2 (64 -> 16), col c
    for (int kb = 0; kb < 8; kb++) {
        float w2v[8];
#pragma unroll
        for (int kk = 0; kk < 8; kk++) w2v[kk] = W2l[(kb * 8 + kk) * 16 + c];
#pragma unroll
        for (int i = 0; i < 4; i++) {
            uint4 a = *(const uint4*)((const char*)hbuf + hoff(r * 4 + i, kb));
            const __half2* hh = (const __half2*)&a;
#pragma unroll
            for (int kk = 0; kk < 4; kk++) {
                float2 f = __half22float2(hh[kk]);
                acc2[i] += f.x * w2v[2 * kk] + f.y * w2v[2 * kk + 1];
            }
        }
    }
    float b2v = lb2l[c];
#pragma unroll
    for (int i = 0; i < 4; i++) a2t[c * 132 + r * 4 + i] = acc2[i] + b2v;
    __syncthreads();
    if (tid < TN) {
        int n = n0 + tid;
        if (n < NN) {
            float lg0 = dbl[0], lg1 = dbl[1], lg2 = dbl[2], lg3 = dbl[3];
#pragma unroll
            for (int k = 0; k < 16; k++) {
                float a = a2t[k * 132 + tid];
                lg0 += a * dwl[k * 4];     lg1 += a * dwl[k * 4 + 1];
                lg2 += a * dwl[k * 4 + 2]; lg3 += a * dwl[k * 4 + 3];
            }
            float mx = fmaxf(fmaxf(lg0, lg1), fmaxf(lg2, lg3));
            float e0 = __expf(lg0 - mx), e1 = __expf(lg1 - mx), e2 = __expf(lg2 - mx), e3 = __expf(lg3 - mx);
            float inv = 1.0f / (e0 + e1 + e2 + e3);
            *(float4*)(out + (size_t)n * 4) = make_float4(e0 * inv, e1 * inv, e2 * inv, e3 * inv);
        }
    }
}

// ---------------- launch ----------------

extern "C" void kernel_launch(void* const* d_in, const int* in_sizes, int n_in,
                              void* d_out, int out_size, void* d_ws, size_t ws_size,
                              hipStream_t stream) {
    const float* x   = (const float*)d_in[0];
    const int*   ei  = (const int*)d_in[1];
    const float* W0  = (const float*)d_in[2];
    const float* as0 = (const float*)d_in[3];
    const float* ad0 = (const float*)d_in[4];
    const float* b0  = (const float*)d_in[5];
    const float* W1  = (const float*)d_in[6];
    const float* as1 = (const float*)d_in[7];
    const float* ad1 = (const float*)d_in[8];
    const float* b1  = (const float*)d_in[9];
    const float* W2  = (const float*)d_in[10];
    const float* as2 = (const float*)d_in[11];
    const float* ad2 = (const float*)d_in[12];
    const float* b2  = (const float*)d_in[13];
    const float* lw1 = (const float*)d_in[14];
    const float* lb1 = (const float*)d_in[15];
    const float* lw2 = (const float*)d_in[16];
    const float* lb2 = (const float*)d_in[17];
    const float* dw  = (const float*)d_in[18];
    const float* db  = (const float*)d_in[19];
    float* out = (float*)d_out;

    char* p = (char*)d_ws;
    size_t off = 0;
    auto alloc = [&](size_t n) -> void* {
        void* r = p + off;
        off = (off + n + 255) & ~(size_t)255;
        return r;
    };
    // double-buffered fp8 tables: gt/gm read layer k while writing layer k+1
    unsigned char* h8a = (unsigned char*)alloc((size_t)NN * 64);
    unsigned char* h8b = (unsigned char*)alloc((size_t)NN * 64);
    float*  esa    = (float*)alloc((size_t)NN * 4 * 4);
    float*  eda    = (float*)alloc((size_t)NN * 4 * 4);
    float*  esb    = (float*)alloc((size_t)NN * 4 * 4);
    float*  edb    = (float*)alloc((size_t)NN * 4 * 4);
    int*    rowptr = (int*)alloc((size_t)(NN + 1) * 4);
    int*    edge_src = (int*)alloc((size_t)EP * 4);
    unsigned int* arena = (unsigned int*)alloc((size_t)NB * SSTRIDE * 4);
    int*    gcur   = (int*)alloc(512 * 4);
    int*    bbase  = (int*)alloc(513 * 4);

    hipMemsetAsync(gcur, 0, 512 * 4, stream);

    partition_k<<<(EP + CHUNK - 1) / CHUNK, 512, 0, stream>>>(ei, gcur, arena);
    bscan_k<<<1, 512, 0, stream>>>(gcur, bbase, rowptr);
    csr_scatter_k<<<NB, 512, 0, stream>>>(bbase, gcur, arena, rowptr, edge_src);

    int nb = (NN + TN - 1) / TN;   // 782

    // layer0 gather (rank-1) + W1 transform -> h8a/esa/eda
    g0t_k<<<nb, 512, 0, stream>>>(x, W0, as0, ad0, b0, rowptr, edge_src, W1, as1, ad1, h8a, esa, eda);
    // layer1 gather + W2 transform -> h8b/esb/edb
    gt_k<<<nb, 512, 0, stream>>>(h8a, esa, eda, rowptr, edge_src, b1, W2, as2, ad2, h8b, esb, edb);
    // layer2 gather + MLP + decoder + softmax -> out
    gm_k<<<nb, 512, 0, stream>>>(h8b, esb, edb, rowptr, edge_src, b2, lw1, lb1, lw2, lb2, dw, db, out);
}

// Round 2
// 358.712 us; speedup vs baseline: 1.1807x; 1.1807x over previous
//
#include <hip/hip_runtime.h>
#include <hip/hip_fp16.h>
#include <math.h>

#define NN 100000
#define EE 1600000
#define EP (EE + NN)   // edges incl. self-loops
#define NEG 0.2f
#define TN 128         // GEMM tile nodes
#define BW 256         // dst-bucket width
#define NB 391         // ceil(NN/BW)
#define CHUNK 4096     // partition chunk (8 edges/thread * 512)
#define SSTRIDE 5120   // arena slots per bucket (mean 4352, max ~4556 = +8 sd)
#define SCAP 5120      // LDS staging capacity in csr_scatter_k

typedef __attribute__((ext_vector_type(2))) float floatx2;

__device__ inline unsigned pk_fp8x4(float a, float b, float c, float d) {
    unsigned r = __builtin_amdgcn_cvt_pk_fp8_f32(a, b, 0u, false);
    r = __builtin_amdgcn_cvt_pk_fp8_f32(c, d, r, true);
    return r;
}

// Wave-level inclusive scan over 64 lanes.
__device__ __forceinline__ int wave_iscan(int v, int lane) {
#pragma unroll
    for (int o = 1; o < 64; o <<= 1) {
        int t = __shfl_up(v, o);
        if (lane >= o) v += t;
    }
    return v;
}

// ---------------- Bucketed CSR build (proven) ----------------

__global__ __launch_bounds__(512) void partition_k(const int* __restrict__ ei, int* __restrict__ gcur,
                                                   unsigned int* __restrict__ arena) {
    __shared__ int lh[512], lcur[512], lbase[512];
    __shared__ int wsum[8];
    __shared__ unsigned int staged[CHUNK];
    __shared__ unsigned short stb[CHUNK];
    int tid = threadIdx.x;
    int lane = tid & 63, wid = tid >> 6;
    int c0 = blockIdx.x * CHUNK;
    int csize = min(CHUNK, EP - c0);
    lh[tid] = 0;
    __syncthreads();
    unsigned int myv[8];
    int myb[8];
#pragma unroll
    for (int i = 0; i < 8; i++) {
        int e = c0 + i * 512 + tid;
        if (e < c0 + csize) {
            int d = (e < EE) ? ei[EE + e] : (e - EE);
            int sv = (e < EE) ? ei[e] : d;
            int b = d >> 8;
            myv[i] = ((unsigned)(d - (b << 8)) << 17) | (unsigned)sv;
            myb[i] = b;
            atomicAdd(&lh[b], 1);
        } else myb[i] = -1;
    }
    __syncthreads();
    int v = lh[tid];
    int isc = wave_iscan(v, lane);
    if (lane == 63) wsum[wid] = isc;
    __syncthreads();
    if (tid == 0) {
        int run = 0;
#pragma unroll
        for (int w = 0; w < 8; w++) { int t = wsum[w]; wsum[w] = run; run += t; }
    }
    __syncthreads();
    int excl = isc - v + wsum[wid];
    lcur[tid] = excl;
    __syncthreads();
#pragma unroll
    for (int i = 0; i < 8; i++) {
        if (myb[i] >= 0) {
            int idx = atomicAdd(&lcur[myb[i]], 1);
            staged[idx] = myv[i];
            stb[idx] = (unsigned short)myb[i];
        }
    }
    __syncthreads();
    if (tid < NB && v > 0) {
        int base = atomicAdd(&gcur[tid], v);
        lbase[tid] = tid * SSTRIDE + base - excl;  // gidx = delta + staged idx
    }
    __syncthreads();
    for (int i = tid; i < csize; i += 512) {
        unsigned int val = staged[i];
        arena[lbase[stb[i]] + i] = val;
    }
}

__global__ __launch_bounds__(512) void bscan_k(const int* __restrict__ gcur, int* __restrict__ bbase,
                                               int* __restrict__ rowptr) {
    __shared__ int s[512];
    int tid = threadIdx.x;
    int v = (tid < NB) ? gcur[tid] : 0;
    s[tid] = v;
    __syncthreads();
    for (int o = 1; o < 512; o <<= 1) {
        int t = (tid >= o) ? s[tid - o] : 0;
        __syncthreads();
        s[tid] += t;
        __syncthreads();
    }
    int excl = s[tid] - v;
    if (tid <= NB) bbase[tid] = excl;   // bbase[NB] == EP
    if (tid == 0) rowptr[NN] = EP;
}

__global__ __launch_bounds__(512) void csr_scatter_k(const int* __restrict__ bbase, const int* __restrict__ gcur,
                                                     const unsigned int* __restrict__ arena,
                                                     int* __restrict__ rowptr, int* __restrict__ edge_src) {
    __shared__ int cnt[256], sc[256];
    __shared__ int wsum[4];
    __shared__ unsigned int stg[SCAP];
    int tid = threadIdx.x;
    int b = blockIdx.x;
    int e0 = bbase[b];
    int sz = gcur[b];
    int abase = b * SSTRIDE;
    if (tid < 256) cnt[tid] = 0;
    __syncthreads();
    for (int i = tid; i < sz; i += 512) {
        unsigned int v = arena[abase + i];
        if (i < SCAP) stg[i] = v;
        atomicAdd(&cnt[v >> 17], 1);
    }
    __syncthreads();
    if (tid < 256) {
        int lane = tid & 63, wid = tid >> 6;
        int v = cnt[tid];
        int isc = wave_iscan(v, lane);
        if (lane == 63) wsum[wid] = isc;
        __syncthreads();
        if (tid == 0) {
            int run = 0;
#pragma unroll
            for (int w = 0; w < 4; w++) { int t = wsum[w]; wsum[w] = run; run += t; }
        }
        __syncthreads();
        int excl = isc - v + wsum[wid];
        int d = (b << 8) + tid;
        if (d < NN) rowptr[d] = e0 + excl;
        sc[tid] = excl;   // becomes per-dst cursor
    } else {
        __syncthreads();
        __syncthreads();
    }
    __syncthreads();
    for (int i = tid; i < sz; i += 512) {
        unsigned int val = (i < SCAP) ? stg[i] : arena[abase + i];
        int dl = val >> 17;
        int p = atomicAdd(&sc[dl], 1);
        edge_src[e0 + p] = (int)(val & 0x1FFFFu);
    }
}

// ---------------- Layer 0: rank-1 fused edge phase ----------------

__global__ __launch_bounds__(256) void gather0_k(const float* __restrict__ x, const float* __restrict__ W0,
                                                 const float* __restrict__ as_, const float* __restrict__ ad_,
                                                 const int* __restrict__ rowptr, const int* __restrict__ edge_src,
                                                 const float* __restrict__ b, __half* __restrict__ hout) {
    __shared__ float W0l[64], asl[64], adl[64], bl[64];
    int tid = threadIdx.x;
    if (tid < 64) { W0l[tid] = W0[tid]; asl[tid] = as_[tid]; adl[tid] = ad_[tid]; bl[tid] = b[tid]; }
    __syncthreads();
    int wv = (blockIdx.x * 256 + tid) >> 6;
    int lane = tid & 63;
    if (wv >= NN) return;
    int q = lane >> 2, head = lane & 3;
    float cs = 0.f, cd = 0.f;
#pragma unroll
    for (int c = 0; c < 16; c++) {
        float w = W0l[head * 16 + c];
        cs += w * asl[head * 16 + c];
        cd += w * adl[head * 16 + c];
    }
    int beg = rowptr[wv], end = rowptr[wv + 1];
    float xd = x[wv];
    float num = 0.f, den = 0.f;
    for (int e0 = beg; e0 < end; e0 += 16) {
        int e = e0 + q;
        bool vld = e < end;
        int ee = vld ? e : (end - 1);
        int src = edge_src[ee];
        float xs = x[src];
        float ev = xs * cs + xd * cd;
        ev = ev > 0.f ? ev : NEG * ev;
        float p = vld ? __expf(ev) : 0.f;
        num += p * xs;
        den += p;
    }
    num += __shfl_xor(num, 4);  num += __shfl_xor(num, 8);
    num += __shfl_xor(num, 16); num += __shfl_xor(num, 32);
    den += __shfl_xor(den, 4);  den += __shfl_xor(den, 8);
    den += __shfl_xor(den, 16); den += __shfl_xor(den, 32);
    float nh = __shfl(num, lane >> 4);
    float dh = __shfl(den, lane >> 4);
    float val = nh / (dh + 1e-16f);
    float hv = val * W0l[lane] + bl[lane];
    hout[((size_t)wv << 6) + lane] = __float2half(hv);
}

// ---------------- 64x64 transform: tiled GEMM + fp8 + es/ed epilogue ----------------
// h8 layout is SPLIT BY HEAD-PAIR: table-lo = h8[0..NN*32) holds channels
// 0-31 (heads 0,1), table-hi = h8[NN*32..) holds channels 32-63 (heads 2,3).
// This keeps each gather pass's random working set (3.2 MB half-table +
// 1.6 MB es) ~ per-XCD L2 (4 MB), vs 9.6 MB combined (r1 fused run measured
// 87 MB HBM fetch/layer = 5x over-fetch from L2 thrash).

__global__ __launch_bounds__(256) void transform64_k(const __half* __restrict__ hin, const float* __restrict__ W,
                                                     const float* __restrict__ as_, const float* __restrict__ ad_,
                                                     unsigned char* __restrict__ h8, float* __restrict__ es, float* __restrict__ ed) {
    __shared__ float At[64 * TN];   // At[k][n], 32 KB
    __shared__ float Wl[64 * 64];   // 16 KB
    int tid = threadIdx.x;
    for (int i = tid; i < 4096; i += 256) Wl[i] = W[i];
    int n0 = blockIdx.x * TN;
    {   // stage h tile transposed into At (fp16 -> fp32)
        int row = tid >> 1, hf = tid & 1;
        int n = n0 + row;
        const uint4* src = (const uint4*)(hin + ((size_t)n << 6) + (hf << 5));
#pragma unroll
        for (int i = 0; i < 4; i++) {
            uint4 raw = make_uint4(0, 0, 0, 0);
            if (n < NN) raw = src[i];
            __half2* hh = (__half2*)&raw;
            int c = (hf << 5) + (i << 3);
#pragma unroll
            for (int j = 0; j < 4; j++) {
                float2 f = __half22float2(hh[j]);
                At[(c + 2 * j) * TN + row]     = f.x;
                At[(c + 2 * j + 1) * TN + row] = f.y;
            }
        }
    }
    __syncthreads();
    int c = tid & 15, r = tid >> 4;
    float acc[8][4];
#pragma unroll
    for (int i = 0; i < 8; i++)
#pragma unroll
        for (int j = 0; j < 4; j++) acc[i][j] = 0.f;
#pragma unroll 4
    for (int k = 0; k < 64; k++) {
        float4 a0 = *(float4*)&At[k * TN + r * 8];
        float4 a1 = *(float4*)&At[k * TN + r * 8 + 4];
        float4 w  = *(float4*)&Wl[k * 64 + c * 4];
        float av[8] = {a0.x, a0.y, a0.z, a0.w, a1.x, a1.y, a1.z, a1.w};
#pragma unroll
        for (int i = 0; i < 8; i++) {
            acc[i][0] += av[i] * w.x; acc[i][1] += av[i] * w.y;
            acc[i][2] += av[i] * w.z; acc[i][3] += av[i] * w.w;
        }
    }
    int head = c >> 2, qq = c & 3;
    float as0v = as_[head * 16 + qq * 4], as1v = as_[head * 16 + qq * 4 + 1];
    float as2v = as_[head * 16 + qq * 4 + 2], as3v = as_[head * 16 + qq * 4 + 3];
    float ad0v = ad_[head * 16 + qq * 4], ad1v = ad_[head * 16 + qq * 4 + 1];
    float ad2v = ad_[head * 16 + qq * 4 + 2], ad3v = ad_[head * 16 + qq * 4 + 3];
    unsigned char* tb = (c < 8) ? h8 : (h8 + (size_t)NN * 32);
    int co = (c & 7) << 2;
#pragma unroll
    for (int i = 0; i < 8; i++) {
        int n = n0 + r * 8 + i;
        float pes = acc[i][0] * as0v + acc[i][1] * as1v + acc[i][2] * as2v + acc[i][3] * as3v;
        float ped = acc[i][0] * ad0v + acc[i][1] * ad1v + acc[i][2] * ad2v + acc[i][3] * ad3v;
        pes += __shfl_xor(pes, 1); pes += __shfl_xor(pes, 2);
        ped += __shfl_xor(ped, 1); ped += __shfl_xor(ped, 2);
        if (n < NN) {
            unsigned rq = pk_fp8x4(acc[i][0], acc[i][1], acc[i][2], acc[i][3]);
            *(unsigned*)(tb + ((size_t)n << 5) + co) = rq;
            if (qq == 0) { es[n * 4 + head] = pes; ed[n * 4 + head] = ped; }
        }
    }
}

// ---------------- Fused edge softmax + gather, ONE HEAD-PAIR per dispatch ----------------
// Proven r12 config preserved: 2 nodes/wave, no k-unroll, packed-f32 accum,
// natural node order. Each pass touches only its 3.2 MB half-table so the
// random reads stay L2-resident per XCD. lane = q*8+j; lane j covers 4
// channels (one fp8 dword); head = pass*2 + (j>>2).

__global__ __launch_bounds__(256) void gather_k(const unsigned char* __restrict__ h8, const float* __restrict__ es,
                                                const float* __restrict__ ed, const int* __restrict__ rowptr,
                                                const int* __restrict__ edge_src, const float* __restrict__ b,
                                                __half* __restrict__ hout, int pass) {
    int pr = (blockIdx.x * 256 + threadIdx.x) >> 6;
    int lane = threadIdx.x & 63;
    int nA = pr * 2;
    if (nA >= NN) return;
    int nB = nA + 1;
    bool hasB = nB < NN;
    int q = lane >> 3, j = lane & 7;
    int head = (pass << 1) + (j >> 2);
    const unsigned char* h8p = h8 + ((size_t)pass * NN * 32) + (j << 2);
    int begA = rowptr[nA], endA = rowptr[nA + 1];
    int begB = hasB ? rowptr[nB] : begA, endB = hasB ? rowptr[nB + 1] : begA;
    float edvA = ed[nA * 4 + head];
    float edvB = hasB ? ed[nB * 4 + head] : 0.f;
    floatx2 accA[2], accB[2];
    accA[0] = (floatx2)(0.f); accA[1] = (floatx2)(0.f);
    accB[0] = (floatx2)(0.f); accB[1] = (floatx2)(0.f);
    float sA = 0.f, sB = 0.f;
    int iters = max((endA - begA + 7) >> 3, (endB - begB + 7) >> 3);
    for (int k = 0; k < iters; k++) {
        int eA = begA + (k << 3) + q;
        int eB = begB + (k << 3) + q;
        bool vA = eA < endA;
        bool vB = eB < endB;
        int srcA = edge_src[vA ? eA : begA];
        int srcB = edge_src[vB ? eB : begB];
        unsigned rawA = *(const unsigned*)(h8p + ((unsigned)srcA << 5));
        float esvA = es[srcA * 4 + head];
        unsigned rawB = *(const unsigned*)(h8p + ((unsigned)srcB << 5));
        float esvB = es[srcB * 4 + head];
        float evA = esvA + edvA; evA = evA > 0.f ? evA : NEG * evA;
        float evB = esvB + edvB; evB = evB > 0.f ? evB : NEG * evB;
        float pA = vA ? __expf(evA) : 0.f;
        float pB = vB ? __expf(evB) : 0.f;
        floatx2 p2A; p2A[0] = pA; p2A[1] = pA;
        floatx2 p2B; p2B[0] = pB; p2B[1] = pB;
        accA[0] += p2A * __builtin_amdgcn_cvt_pk_f32_fp8(rawA, false);
        accA[1] += p2A * __builtin_amdgcn_cvt_pk_f32_fp8(rawA, true);
        accB[0] += p2B * __builtin_amdgcn_cvt_pk_f32_fp8(rawB, false);
        accB[1] += p2B * __builtin_amdgcn_cvt_pk_f32_fp8(rawB, true);
        sA += pA;
        sB += pB;
    }
    float fA[4] = {accA[0][0], accA[0][1], accA[1][0], accA[1][1]};
    float fB[4] = {accB[0][0], accB[0][1], accB[1][0], accB[1][1]};
#pragma unroll
    for (int t = 0; t < 4; t++) {
        fA[t] += __shfl_xor(fA[t], 8);
        fA[t] += __shfl_xor(fA[t], 16);
        fA[t] += __shfl_xor(fA[t], 32);
        fB[t] += __shfl_xor(fB[t], 8);
        fB[t] += __shfl_xor(fB[t], 16);
        fB[t] += __shfl_xor(fB[t], 32);
    }
    sA += __shfl_xor(sA, 8); sA += __shfl_xor(sA, 16); sA += __shfl_xor(sA, 32);
    sB += __shfl_xor(sB, 8); sB += __shfl_xor(sB, 16); sB += __shfl_xor(sB, 32);
    if (q == 0) {
        float4 bv = *(const float4*)(b + (pass << 5) + (j << 2));
        {
            float inv = 1.0f / (sA + 1e-16f);
            union { __half2 h2[2]; uint2 u; } pk;
            pk.h2[0] = __floats2half2_rn(fA[0] * inv + bv.x, fA[1] * inv + bv.y);
            pk.h2[1] = __floats2half2_rn(fA[2] * inv + bv.z, fA[3] * inv + bv.w);
            *(uint2*)(hout + ((size_t)nA << 6) + (pass << 5) + (j << 2)) = pk.u;
        }
        if (hasB) {
            float inv = 1.0f / (sB + 1e-16f);
            union { __half2 h2[2]; uint2 u; } pk;
            pk.h2[0] = __floats2half2_rn(fB[0] * inv + bv.x, fB[1] * inv + bv.y);
            pk.h2[1] = __floats2half2_rn(fB[2] * inv + bv.z, fB[3] * inv + bv.w);
            *(uint2*)(hout + ((size_t)nB << 6) + (pass << 5) + (j << 2)) = pk.u;
        }
    }
}

// ---------------- MLP + decoder + softmax (tiled, fused) ----------------

__global__ __launch_bounds__(256) void mlp_k(const __half* __restrict__ h, const float* __restrict__ lw1,
                                             const float* __restrict__ lb1, const float* __restrict__ lw2,
                                             const float* __restrict__ lb2, const float* __restrict__ dw,
                                             const float* __restrict__ db, float* __restrict__ out) {
    __shared__ float At[64 * TN];   // h tile transposed; reused as a1t after GEMM1
    __shared__ float W1l[4096];     // lw1; reused as a2t (needs 16*TN=2048)
    __shared__ float W2l[1024];
    __shared__ float dwl[64];
    __shared__ float dbl[4];
    int tid = threadIdx.x;
    for (int i = tid; i < 4096; i += 256) W1l[i] = lw1[i];
    for (int i = tid; i < 1024; i += 256) W2l[i] = lw2[i];
    if (tid < 64) dwl[tid] = dw[tid];
    if (tid < 4) dbl[tid] = db[tid];
    int n0 = blockIdx.x * TN;
    {   // stage
        int row = tid >> 1, hf = tid & 1;
        int n = n0 + row;
        const uint4* src = (const uint4*)(h + ((size_t)n << 6) + (hf << 5));
#pragma unroll
        for (int i = 0; i < 4; i++) {
            uint4 raw = make_uint4(0, 0, 0, 0);
            if (n < NN) raw = src[i];
            __half2* hh = (__half2*)&raw;
            int c = (hf << 5) + (i << 3);
#pragma unroll
            for (int j = 0; j < 4; j++) {
                float2 f = __half22float2(hh[j]);
                At[(c + 2 * j) * TN + row]     = f.x;
                At[(c + 2 * j + 1) * TN + row] = f.y;
            }
        }
    }
    __syncthreads();
    int c = tid & 15, r = tid >> 4;
    float acc[8][4];
#pragma unroll
    for (int i = 0; i < 8; i++)
#pragma unroll
        for (int j = 0; j < 4; j++) acc[i][j] = 0.f;
#pragma unroll 4
    for (int k = 0; k < 64; k++) {
        float4 a0 = *(float4*)&At[k * TN + r * 8];
        float4 a1 = *(float4*)&At[k * TN + r * 8 + 4];
        float4 w  = *(float4*)&W1l[k * 64 + c * 4];
        float av[8] = {a0.x, a0.y, a0.z, a0.w, a1.x, a1.y, a1.z, a1.w};
#pragma unroll
        for (int i = 0; i < 8; i++) {
            acc[i][0] += av[i] * w.x; acc[i][1] += av[i] * w.y;
            acc[i][2] += av[i] * w.z; acc[i][3] += av[i] * w.w;
        }
    }
    float b1v0 = lb1[c * 4], b1v1 = lb1[c * 4 + 1], b1v2 = lb1[c * 4 + 2], b1v3 = lb1[c * 4 + 3];
    __syncthreads();
#pragma unroll
    for (int i = 0; i < 8; i++) {
        int n = r * 8 + i;
        At[(c * 4 + 0) * TN + n] = fmaxf(acc[i][0] + b1v0, 0.f);
        At[(c * 4 + 1) * TN + n] = fmaxf(acc[i][1] + b1v1, 0.f);
        At[(c * 4 + 2) * TN + n] = fmaxf(acc[i][2] + b1v2, 0.f);
        At[(c * 4 + 3) * TN + n] = fmaxf(acc[i][3] + b1v3, 0.f);
    }
    __syncthreads();
    float acc2[8];
#pragma unroll
    for (int i = 0; i < 8; i++) acc2[i] = 0.f;
#pragma unroll 4
    for (int k = 0; k < 64; k++) {
        float4 a0 = *(float4*)&At[k * TN + r * 8];
        float4 a1 = *(float4*)&At[k * TN + r * 8 + 4];
        float wv = W2l[k * 16 + c];
        acc2[0] += a0.x * wv; acc2[1] += a0.y * wv; acc2[2] += a0.z * wv; acc2[3] += a0.w * wv;
        acc2[4] += a1.x * wv; acc2[5] += a1.y * wv; acc2[6] += a1.z * wv; acc2[7] += a1.w * wv;
    }
    float b2v = lb2[c];
#pragma unroll
    for (int i = 0; i < 8; i++) W1l[c * TN + r * 8 + i] = acc2[i] + b2v;  // a2t[col][node]
    __syncthreads();
    if (tid < TN) {
        int n = n0 + tid;
        if (n < NN) {
            float lg0 = dbl[0], lg1 = dbl[1], lg2 = dbl[2], lg3 = dbl[3];
#pragma unroll
            for (int k = 0; k < 16; k++) {
                float a = W1l[k * TN + tid];
                lg0 += a * dwl[k * 4];     lg1 += a * dwl[k * 4 + 1];
                lg2 += a * dwl[k * 4 + 2]; lg3 += a * dwl[k * 4 + 3];
            }
            float mx = fmaxf(fmaxf(lg0, lg1), fmaxf(lg2, lg3));
            float e0 = __expf(lg0 - mx), e1 = __expf(lg1 - mx), e2 = __expf(lg2 - mx), e3 = __expf(lg3 - mx);
            float inv = 1.0f / (e0 + e1 + e2 + e3);
            *(float4*)(out + (size_t)n * 4) = make_float4(e0 * inv, e1 * inv, e2 * inv, e3 * inv);
        }
    }
}

// ---------------- launch ----------------

extern "C" void kernel_launch(void* const* d_in, const int* in_sizes, int n_in,
                              void* d_out, int out_size, void* d_ws, size_t ws_size,
                              hipStream_t stream) {
    const float* x   = (const float*)d_in[0];
    const int*   ei  = (const int*)d_in[1];
    const float* W0  = (const float*)d_in[2];
    const float* as0 = (const float*)d_in[3];
    const float* ad0 = (const float*)d_in[4];
    const float* b0  = (const float*)d_in[5];
    const float* W1  = (const float*)d_in[6];
    const float* as1 = (const float*)d_in[7];
    const float* ad1 = (const float*)d_in[8];
    const float* b1  = (const float*)d_in[9];
    const float* W2  = (const float*)d_in[10];
    const float* as2 = (const float*)d_in[11];
    const float* ad2 = (const float*)d_in[12];
    const float* b2  = (const float*)d_in[13];
    const float* lw1 = (const float*)d_in[14];
    const float* lb1 = (const float*)d_in[15];
    const float* lw2 = (const float*)d_in[16];
    const float* lb2 = (const float*)d_in[17];
    const float* dw  = (const float*)d_in[18];
    const float* db  = (const float*)d_in[19];
    float* out = (float*)d_out;

    char* p = (char*)d_ws;
    size_t off = 0;
    auto alloc = [&](size_t n) -> void* {
        void* r = p + off;
        off = (off + n + 255) & ~(size_t)255;
        return r;
    };
    __half* hB     = (__half*)alloc((size_t)NN * 64 * 2);
    __half* hC     = (__half*)alloc((size_t)NN * 64 * 2);
    unsigned char* h8 = (unsigned char*)alloc((size_t)NN * 64);   // [2][NN][32] split by head-pair
    float*  es     = (float*)alloc((size_t)NN * 4 * 4);
    float*  ed     = (float*)alloc((size_t)NN * 4 * 4);
    int*    rowptr = (int*)alloc((size_t)(NN + 1) * 4);
    int*    edge_src = (int*)alloc((size_t)EP * 4);
    unsigned int* arena = (unsigned int*)alloc((size_t)NB * SSTRIDE * 4);
    int*    gcur   = (int*)alloc(512 * 4);
    int*    bbase  = (int*)alloc(513 * 4);

    hipMemsetAsync(gcur, 0, 512 * 4, stream);

    partition_k<<<(EP + CHUNK - 1) / CHUNK, 512, 0, stream>>>(ei, gcur, arena);
    bscan_k<<<1, 512, 0, stream>>>(gcur, bbase, rowptr);
    csr_scatter_k<<<NB, 512, 0, stream>>>(bbase, gcur, arena, rowptr, edge_src);

    int nb_tile = (NN + TN - 1) / TN;       // 782
    int nb_wave = (NN + 3) / 4;             // 25000
    int nb_pair = ((NN + 1) / 2 + 3) / 4;   // 12500 (2 nodes per wave)

    gather0_k<<<nb_wave, 256, 0, stream>>>(x, W0, as0, ad0, rowptr, edge_src, b0, hB);

    transform64_k<<<nb_tile, 256, 0, stream>>>(hB, W1, as1, ad1, h8, es, ed);
    gather_k<<<nb_pair, 256, 0, stream>>>(h8, es, ed, rowptr, edge_src, b1, hC, 0);
    gather_k<<<nb_pair, 256, 0, stream>>>(h8, es, ed, rowptr, edge_src, b1, hC, 1);

    transform64_k<<<nb_tile, 256, 0, stream>>>(hC, W2, as2, ad2, h8, es, ed);
    gather_k<<<nb_pair, 256, 0, stream>>>(h8, es, ed, rowptr, edge_src, b2, hB, 0);
    gather_k<<<nb_pair, 256, 0, stream>>>(h8, es, ed, rowptr, edge_src, b2, hB, 1);

    mlp_k<<<nb_tile, 256, 0, stream>>>(hB, lw1, lb1, lw2, lb2, dw, db, out);
}